// Round 11
// baseline (136.407 us; speedup 1.0000x reference)
//
#include <hip/hip_runtime.h>

#define DEVINL __device__ __forceinline__

typedef __attribute__((ext_vector_type(4))) float f32x4;
typedef __attribute__((ext_vector_type(8))) short short8;

constexpr int kBN = 12, kC = 256, kH = 40, kW = 100;
constexpr int kNQ = kH * kW;      // 4000
constexpr int kM = kBN * kNQ;     // 48000

DEVINL float bflo(uint p) { union { uint i; float f; } v; v.i = p << 16; return v.f; }
DEVINL float bfhi(uint p) { union { uint i; float f; } v; v.i = p & 0xffff0000u; return v.f; }
DEVINL ushort f2bf(float f) {
  union { float f; uint i; } v; v.f = f;
  uint i = v.i;
  return (ushort)((i + 0x7fffu + ((i >> 16) & 1u)) >> 16);  // RNE
}
DEVINL uint pack2(float a, float b) { return (uint)f2bf(a) | ((uint)f2bf(b) << 16); }

DEVINL void mfma_bf16(f32x4& acc, short8 a, short8 b) {
  acc = __builtin_amdgcn_mfma_f32_16x16x32_bf16(a, b, acc, 0, 0, 0);
}

DEVINL void gload16(const ushort* g, char* lds) {
  __builtin_amdgcn_global_load_lds(
      (const __attribute__((address_space(1))) uint*)g,
      (__attribute__((address_space(3))) uint*)lds, 16, 0, 0);
}

DEVINL void acc8(float* acc, uint4 d, float wv) {
  acc[0] += wv * bflo(d.x); acc[1] += wv * bfhi(d.x);
  acc[2] += wv * bflo(d.y); acc[3] += wv * bfhi(d.y);
  acc[4] += wv * bflo(d.z); acc[5] += wv * bfhi(d.z);
  acc[6] += wv * bflo(d.w); acc[7] += wv * bfhi(d.w);
}

// ---------------- K0: all 4 weight transposes in one launch ------------------
__global__ __launch_bounds__(256) void k_wt_all(const float* __restrict__ Wv,
                                                const float* __restrict__ Woff,
                                                const float* __restrict__ Wattn,
                                                const float* __restrict__ Wout,
                                                ushort* __restrict__ WvT,
                                                ushort* __restrict__ WoffT,
                                                ushort* __restrict__ WattnT,
                                                ushort* __restrict__ WoutT) {
  int idx = blockIdx.x * 256 + threadIdx.x;
  const float* W; ushort* WT; int N, base;
  if (idx < 65536)       { W = Wv;    WT = WvT;    N = 256; base = 0; }
  else if (idx < 81920)  { W = Woff;  WT = WoffT;  N = 64;  base = 65536; }
  else if (idx < 90112)  { W = Wattn; WT = WattnT; N = 32;  base = 81920; }
  else if (idx < 155648) { W = Wout;  WT = WoutT;  N = 256; base = 90112; }
  else return;
  int i = idx - base;
  int n = i >> 8, k = i & 255;       // K = 256 for all
  WT[i] = f2bf(W[k * N + n]);
}

// ---------------- K1: img NCHW f32 -> feat [b][q][c] bf16 --------------------
__global__ __launch_bounds__(256) void k_transpose(const float* __restrict__ img,
                                                   ushort* __restrict__ feat) {
  __shared__ ushort tile[64][66];
  int b = blockIdx.z, c0 = blockIdx.y * 64, q0 = blockIdx.x * 64;
  int t = threadIdx.x;
  int ql = t & 63, cl = t >> 6;
#pragma unroll
  for (int i = 0; i < 16; ++i) {
    int c = cl + i * 4, q = q0 + ql;
    float v = (q < kNQ) ? img[(size_t)(b * kC + c0 + c) * kNQ + q] : 0.f;
    tile[c][ql] = f2bf(v);
  }
  __syncthreads();
  int cc = t & 63, qr = t >> 6;
#pragma unroll
  for (int i = 0; i < 16; ++i) {
    int qlo = qr + i * 4, q = q0 + qlo;
    if (q < kNQ) feat[(size_t)(b * kNQ + q) * kC + c0 + cc] = tile[cc][qlo];
  }
}

// ---------------- K3: FUSED warp-gather + MFMA GEMM v (BM=64, BN=256) --------
// Phase A (gather): 8 passes; 32 lanes/q compute the bilinear-warped A-row and
// write it DIRECTLY into the swizzled LDS A-tile [64 rows][512 B]
// (slot XOR (row>>1)&3 within each 64B K-group — matches GEMM read swizzle).
// Phase B (GEMM): K-loop stages only B (double-buffered, counted vmcnt(4)).
// Grid 756, bijective XCD swizzle by (b, tile) -> feat slab L2-resident.
// Epilogue: v head-major bf16 [b][h][q][32].
__global__ __launch_bounds__(256) void k_gemmv_fused(const ushort* __restrict__ feat,
                                                     const float* __restrict__ grid,
                                                     const ushort* __restrict__ BT,
                                                     const float* __restrict__ bias,
                                                     ushort* __restrict__ Obf) {
  extern __shared__ char smem[];
  char* Afull = smem;                 // [64][512B] = 32768 B, swizzled
  const int t = threadIdx.x, wave = t >> 6, lane = t & 63;
  const int l15 = lane & 15, l4 = lane >> 4;

  // bijective XCD swizzle, nwg = 756: q=94, r=4
  int orig = blockIdx.x;
  int xcd = orig % 8, ii = orig / 8;
  int n = (xcd < 4 ? xcd * 95 : 380 + (xcd - 4) * 94) + ii;
  const int b = n / 63, mb = n % 63;
  const int q0 = mb * 64;
  const int nrows = (kNQ - q0 < 64) ? (kNQ - q0) : 64;
  const int n0w = wave * 64;

  // ---- phase A: warp gather -> LDS A-tile ----
  {
    const int g = t & 31;               // 16B chunk of the 512B row
    const int qa = t >> 5;              // q-sub-index within pass (0..7)
    const ushort* fb = feat + (size_t)b * kNQ * kC + g * 8;
#pragma unroll 1
    for (int pass = 0; pass < 8; ++pass) {
      int ql = pass * 8 + qa;
      int qlc = (ql < nrows) ? ql : (nrows - 1);
      size_t gq = (size_t)b * kNQ + q0 + qlc;
      float gx = grid[gq * 2 + 0] * kW - 0.5f;
      float gy = grid[gq * 2 + 1] * kH - 0.5f;
      float x0f = floorf(gx), y0f = floorf(gy);
      int x0 = (int)x0f, y0 = (int)y0f;
      float wx = gx - x0f, wy = gy - y0f;
      float acc[8];
#pragma unroll
      for (int i = 0; i < 8; ++i) acc[i] = 0.f;
#pragma unroll
      for (int ty = 0; ty < 2; ++ty) {
        int iy = y0 + ty;
        if (iy < 0 || iy >= kH) continue;
        float wyv = ty ? wy : 1.f - wy;
#pragma unroll
        for (int tx = 0; tx < 2; ++tx) {
          int ix = x0 + tx;
          if (ix < 0 || ix >= kW) continue;
          float wv = wyv * (tx ? wx : 1.f - wx);
          uint4 d = *(const uint4*)(fb + (size_t)(iy * kW + ix) * kC);
          acc8(acc, d, wv);
        }
      }
      uint o[4] = {pack2(acc[0], acc[1]), pack2(acc[2], acc[3]),
                   pack2(acc[4], acc[5]), pack2(acc[6], acc[7])};
      int sslot = (g & 3) ^ ((ql >> 1) & 3);
      *(uint4*)(Afull + ql * 512 + (g >> 2) * 64 + sslot * 16) = *(uint4*)o;
    }
  }
  __syncthreads();

  // ---- phase B: GEMM, B-only double-buffered staging ----
  const int ra = t >> 2, ca = t & 3;
  const int sca = ca ^ ((ra >> 1) & 3);
  const ushort* gB = BT + (size_t)ra * 256 + sca * 8;

  f32x4 acc[4][4];
#pragma unroll
  for (int i = 0; i < 4; ++i)
#pragma unroll
    for (int j = 0; j < 4; ++j) acc[i][j] = (f32x4)0.f;

  auto STAGE_B = [&](int buf, int kk) {
    char* Bsb = smem + 32768 + buf * 16384;
#pragma unroll
    for (int i = 0; i < 4; ++i)
      gload16(gB + (size_t)i * 64 * 256 + kk, Bsb + (i * 256 + t) * 16);
  };

  STAGE_B(0, 0);
  int cur = 0;
#pragma unroll 1
  for (int step = 0; step < 8; ++step) {
    if (step < 7) {
      STAGE_B(cur ^ 1, (step + 1) * 32);
      asm volatile("s_waitcnt vmcnt(4)" ::: "memory");
    } else {
      asm volatile("s_waitcnt vmcnt(0)" ::: "memory");
    }
    __builtin_amdgcn_s_barrier();
    asm volatile("" ::: "memory");
    char* Bsb = smem + 32768 + cur * 16384;
    short8 af[4], bf[4];
#pragma unroll
    for (int mf = 0; mf < 4; ++mf) {
      int r = mf * 16 + l15;
      int sl = l4 ^ ((r >> 1) & 3);
      af[mf] = *(const short8*)(Afull + r * 512 + step * 64 + sl * 16);
    }
#pragma unroll
    for (int nf = 0; nf < 4; ++nf) {
      int r = n0w + nf * 16 + l15;
      int sl = l4 ^ ((r >> 1) & 3);
      bf[nf] = *(const short8*)(Bsb + r * 64 + sl * 16);
    }
#pragma unroll
    for (int mf = 0; mf < 4; ++mf)
#pragma unroll
      for (int nf = 0; nf < 4; ++nf) mfma_bf16(acc[mf][nf], af[mf], bf[nf]);
    asm volatile("" ::: "memory");
    __builtin_amdgcn_s_barrier();
    cur ^= 1;
  }

  // epilogue: v head-major bf16
#pragma unroll
  for (int mf = 0; mf < 4; ++mf) {
    if (mf * 16 >= nrows) continue;
    int q = q0 + mf * 16 + l4 * 4;
#pragma unroll
    for (int nf = 0; nf < 4; ++nf) {
      int col = n0w + nf * 16 + l15;
      float bv = bias[col];
      int h = col >> 5, ch = col & 31;
      ushort* dst = Obf + (size_t)(b * 8 + h) * kNQ * 32 + ch;
#pragma unroll
      for (int j = 0; j < 4; ++j)
        dst[(size_t)(q + j) * 32] = f2bf(acc[mf][nf][j] + bv);
    }
  }
}

// ---------------- K6: MFMA GEMM out (BM=64, BN=256), counted-vmcnt dbuf ------
// NCHW fp32 out: acc + bias + resid, via per-wave LDS transpose.
__global__ __launch_bounds__(256) void k_gemmout(const ushort* __restrict__ A,
                                                 const ushort* __restrict__ BT,
                                                 const float* __restrict__ bias,
                                                 float* __restrict__ Ofp,
                                                 const float* __restrict__ resid) {
  extern __shared__ char smem[];
  const int t = threadIdx.x, wave = t >> 6, lane = t & 63;
  const int l15 = lane & 15, l4 = lane >> 4;
  const int b = blockIdx.x / 63, mb = blockIdx.x % 63;
  const int q0 = mb * 64;
  const int nrows = (kNQ - q0 < 64) ? (kNQ - q0) : 64;
  const int n0w = wave * 64;
  const int ra = t >> 2, ca = t & 3;
  const int rac = (ra < nrows) ? ra : (nrows - 1);   // clamp: uniform 5 loads
  const int sca = ca ^ ((ra >> 1) & 3);
  const ushort* gA = A + ((size_t)b * kNQ + q0 + rac) * 256 + sca * 8;
  const ushort* gB = BT + (size_t)ra * 256 + sca * 8;

  f32x4 acc[4][4];
#pragma unroll
  for (int i = 0; i < 4; ++i)
#pragma unroll
    for (int j = 0; j < 4; ++j) acc[i][j] = (f32x4)0.f;

  auto STAGE = [&](int buf, int kk) {
    char* Asb = smem + buf * 20480;
    char* Bsb = Asb + 4096;
    gload16(gA + kk, Asb + t * 16);
#pragma unroll
    for (int i = 0; i < 4; ++i)
      gload16(gB + (size_t)i * 64 * 256 + kk, Bsb + (i * 256 + t) * 16);
  };

  STAGE(0, 0);
  int cur = 0;
#pragma unroll 1
  for (int step = 0; step < 8; ++step) {
    if (step < 7) {
      STAGE(cur ^ 1, (step + 1) * 32);
      asm volatile("s_waitcnt vmcnt(5)" ::: "memory");
    } else {
      asm volatile("s_waitcnt vmcnt(0)" ::: "memory");
    }
    __builtin_amdgcn_s_barrier();
    asm volatile("" ::: "memory");
    char* Asb = smem + cur * 20480;
    char* Bsb = Asb + 4096;
    short8 af[4], bf[4];
#pragma unroll
    for (int mf = 0; mf < 4; ++mf) {
      int r = mf * 16 + l15;
      int sl = l4 ^ ((r >> 1) & 3);
      af[mf] = *(const short8*)(Asb + r * 64 + sl * 16);
    }
#pragma unroll
    for (int nf = 0; nf < 4; ++nf) {
      int r = n0w + nf * 16 + l15;
      int sl = l4 ^ ((r >> 1) & 3);
      bf[nf] = *(const short8*)(Bsb + r * 64 + sl * 16);
    }
#pragma unroll
    for (int mf = 0; mf < 4; ++mf)
#pragma unroll
      for (int nf = 0; nf < 4; ++nf) mfma_bf16(acc[mf][nf], af[mf], bf[nf]);
    asm volatile("" ::: "memory");
    __builtin_amdgcn_s_barrier();
    cur ^= 1;
  }

  // per-wave transpose scratch: [16 cols][68 rows] fp32 = 4352 B per wave
  float* Tw = (float*)(smem + wave * 4352);
#pragma unroll
  for (int nf = 0; nf < 4; ++nf) {
    float bv = bias[n0w + nf * 16 + l15];
#pragma unroll
    for (int mf = 0; mf < 4; ++mf)
#pragma unroll
      for (int j = 0; j < 4; ++j)
        Tw[l15 * 68 + mf * 16 + l4 * 4 + j] = acc[mf][nf][j] + bv;
    int c = l15, rs = l4 * 16;
    if (rs < nrows) {
      int col = n0w + nf * 16 + c;
      size_t gi = ((size_t)b * kC + col) * kNQ + q0 + rs;
#pragma unroll
      for (int k = 0; k < 4; ++k) {
        float4 tv = *(float4*)(&Tw[c * 68 + rs + k * 4]);
        float4 rv = *(const float4*)(resid + gi + k * 4);
        tv.x += rv.x; tv.y += rv.y; tv.z += rv.z; tv.w += rv.w;
        *(float4*)(Ofp + gi + k * 4) = tv;
      }
    }
  }
}

// ---------------- K4: off+attn GEMM (BM=64, BN=96) 2-phase dbuf + softmax ----
// samp layout: [b][h][q][p] packed 12 B {sx, sy, w}
__global__ __launch_bounds__(256) void k_offattn(const ushort* __restrict__ A,
                                                 const ushort* __restrict__ WoffT,
                                                 const ushort* __restrict__ WattnT,
                                                 const float* __restrict__ boff,
                                                 const float* __restrict__ battn,
                                                 const float* __restrict__ refp,
                                                 float* __restrict__ samp) {
  extern __shared__ char smem[];
  float* T = (float*)smem;    // epilogue: [64][101] fp32 = 25856 B (aliases bufs)
  const int t = threadIdx.x, wave = t >> 6, lane = t & 63;
  const int l15 = lane & 15, l4 = lane >> 4;
  const int b = blockIdx.x / 63, mb = blockIdx.x % 63;
  const int q0 = mb * 64;
  const int nrows = (kNQ - q0 < 64) ? (kNQ - q0) : 64;
  const int wr = wave >> 1, wc = wave & 1;
  const int ra = t >> 2, ca = t & 3;
  const int sca = ca ^ ((ra >> 1) & 3);
  const ushort* gA  = A + ((size_t)b * kNQ + q0 + ra) * 256 + sca * 8;
  const ushort* gB0 = WoffT + (size_t)ra * 256 + sca * 8;
  const ushort* gB1 = WattnT + (size_t)ra * 256 + sca * 8;  // t<128 (ra<32)
  const bool doA = (ra < nrows);

  f32x4 acc[2][3];
#pragma unroll
  for (int i = 0; i < 2; ++i)
#pragma unroll
    for (int j = 0; j < 3; ++j) acc[i][j] = (f32x4)0.f;

  auto STAGE = [&](int buf, int kk) {
    char* Asb = smem + buf * 10240;
    char* Bsb = Asb + 4096;
    if (doA) gload16(gA + kk, Asb + t * 16);
    gload16(gB0 + kk, Bsb + t * 16);
    if (t < 128) gload16(gB1 + kk, Bsb + (256 + t) * 16);
  };

  STAGE(0, 0);
  __syncthreads();
  int cur = 0;
#pragma unroll 1
  for (int step = 0; step < 8; ++step) {
    if (step < 7) STAGE(cur ^ 1, (step + 1) * 32);
    char* Asb = smem + cur * 10240;
    char* Bsb = Asb + 4096;
    short8 af[2], bf[3];
#pragma unroll
    for (int mf = 0; mf < 2; ++mf) {
      int r = wr * 32 + mf * 16 + l15;
      int sl = l4 ^ ((r >> 1) & 3);
      af[mf] = *(const short8*)(Asb + r * 64 + sl * 16);
    }
#pragma unroll
    for (int nf = 0; nf < 3; ++nf) {
      int r = wc * 48 + nf * 16 + l15;
      int sl = l4 ^ ((r >> 1) & 3);
      bf[nf] = *(const short8*)(Bsb + r * 64 + sl * 16);
    }
#pragma unroll
    for (int mf = 0; mf < 2; ++mf)
#pragma unroll
      for (int nf = 0; nf < 3; ++nf) mfma_bf16(acc[mf][nf], af[mf], bf[nf]);
    __syncthreads();
    cur ^= 1;
  }

#pragma unroll
  for (int nf = 0; nf < 3; ++nf) {
    int col = wc * 48 + nf * 16 + l15;
    float bv = (col < 64) ? boff[col] : battn[col - 64];
#pragma unroll
    for (int mf = 0; mf < 2; ++mf)
#pragma unroll
      for (int j = 0; j < 4; ++j) {
        int row = wr * 32 + mf * 16 + l4 * 4 + j;
        T[row * 101 + col] = acc[mf][nf][j] + bv;
      }
  }
  __syncthreads();
  int row = t >> 2;
  if (row < nrows) {
    int q = q0 + row;
    float refx = refp[((size_t)b * kNQ + q) * 2 + 0] * kW - 0.5f;
    float refy = refp[((size_t)b * kNQ + q) * 2 + 1] * kH - 0.5f;
#pragma unroll
    for (int hi2 = 0; hi2 < 2; ++hi2) {
      int h = (t & 3) + hi2 * 4;
      float sx[4], sy[4], lg[4];
#pragma unroll
      for (int p = 0; p < 4; ++p) {
        sx[p] = refx + T[row * 101 + h * 8 + p * 2 + 0];
        sy[p] = refy + T[row * 101 + h * 8 + p * 2 + 1];
        lg[p] = T[row * 101 + 64 + h * 4 + p];
      }
      float mx = fmaxf(fmaxf(lg[0], lg[1]), fmaxf(lg[2], lg[3]));
      float e[4], s = 0.f;
#pragma unroll
      for (int p = 0; p < 4; ++p) { e[p] = __expf(lg[p] - mx); s += e[p]; }
      float inv = 1.f / s;
      float* dst = samp + (((size_t)(b * 8 + h) * kNQ + q) * 4) * 3;
#pragma unroll
      for (int p = 0; p < 4; ++p) {
        dst[p * 3 + 0] = sx[p];
        dst[p * 3 + 1] = sy[p];
        dst[p * 3 + 2] = e[p] * inv;
      }
    }
  }
}

// ---------------- K5: deformable sampling + attention aggregate --------------
__global__ __launch_bounds__(256) void k_sample(const ushort* __restrict__ v,
                                                const float* __restrict__ samp,
                                                ushort* __restrict__ agg) {
  int orig = blockIdx.x;
  int n = (orig & 7) * 756 + (orig >> 3);      // bijective, 6048 = 8*756
  int plane = n / 63, chunk = n - plane * 63;  // 96 planes x 63 chunks
  int t = threadIdx.x;
  int ql = t >> 2, g = t & 3;                  // 64 q per block, 4 lanes per q
  int q = chunk * 64 + ql;
  if (q >= kNQ) return;
  int b = plane >> 3, h = plane & 7;
  const ushort* pv = v + (size_t)plane * kNQ * 32 + g * 8;
  const int lane = t & 63, gbase = lane & ~3;

  const float* sp = samp + (((size_t)plane * kNQ + q) * 4 + g) * 3;
  float myx = sp[0], myy = sp[1], myw = sp[2];   // lane g owns point g
  float acc[8];
#pragma unroll
  for (int i = 0; i < 8; ++i) acc[i] = 0.f;
#pragma unroll
  for (int p = 0; p < 4; ++p) {
    float sxp = __shfl(myx, gbase + p);
    float syp = __shfl(myy, gbase + p);
    float wp  = __shfl(myw, gbase + p);
    float x0f = floorf(sxp), y0f = floorf(syp);
    int x0 = (int)x0f, y0 = (int)y0f;
    float wx = sxp - x0f, wy = syp - y0f;
#pragma unroll
    for (int ty = 0; ty < 2; ++ty) {
      int iy = y0 + ty;
      if (iy < 0 || iy >= kH) continue;
      float wyv = ty ? wy : 1.f - wy;
#pragma unroll
      for (int tx = 0; tx < 2; ++tx) {
        int ix = x0 + tx;
        if (ix < 0 || ix >= kW) continue;
        float wv = wp * wyv * (tx ? wx : 1.f - wx);
        uint4 d = *(const uint4*)(pv + (size_t)(iy * kW + ix) * 32);
        acc8(acc, d, wv);
      }
    }
  }
  uint o[4] = {pack2(acc[0], acc[1]), pack2(acc[2], acc[3]),
               pack2(acc[4], acc[5]), pack2(acc[6], acc[7])};
  *(uint4*)(agg + ((size_t)b * kNQ + q) * kC + h * 32 + g * 8) = *(uint4*)o;
}

extern "C" void kernel_launch(void* const* d_in, const int* in_sizes, int n_in,
                              void* d_out, int out_size, void* d_ws, size_t ws_size,
                              hipStream_t stream) {
  const float* img   = (const float*)d_in[0];
  const float* grid  = (const float*)d_in[1];
  const float* refp  = (const float*)d_in[2];
  const float* Wv    = (const float*)d_in[3];
  const float* bv    = (const float*)d_in[4];
  const float* Woff  = (const float*)d_in[5];
  const float* boff  = (const float*)d_in[6];
  const float* Wattn = (const float*)d_in[7];
  const float* battn = (const float*)d_in[8];
  const float* Wout  = (const float*)d_in[9];
  const float* bout  = (const float*)d_in[10];
  float* out = (float*)d_out;

  char* ws = (char*)d_ws;
  const size_t SZ = (size_t)kM * kC * 2;  // 24.576 MB per bf16 [M][C] buffer
  ushort* feat   = (ushort*)(ws);
  ushort* aggb   = (ushort*)(ws + SZ);               // agg [b][q][c]
  ushort* vbuf   = (ushort*)(ws + 2 * SZ);           // [b][h][q][32] head-major
  float*  samp   = (float*)(ws + 3 * SZ);            // [b][h][q][p]{x,y,w} 18.4 MB
  ushort* WvT    = (ushort*)(ws + 4 * SZ);
  ushort* WoffT  = (ushort*)(ws + 4 * SZ + 131072);
  ushort* WattnT = (ushort*)(ws + 4 * SZ + 131072 + 32768);
  ushort* WoutT  = (ushort*)(ws + 4 * SZ + 131072 + 32768 + 16384);

  k_wt_all<<<608, 256, 0, stream>>>(Wv, Woff, Wattn, Wout, WvT, WoffT, WattnT, WoutT);
  k_transpose<<<dim3(63, 4, 12), 256, 0, stream>>>(img, feat);
  k_gemmv_fused<<<756, 256, 65536, stream>>>(feat, grid, WvT, bv, vbuf);
  k_offattn<<<756, 256, 25856, stream>>>(feat, WoffT, WattnT, boff, battn, refp, samp);
  k_sample<<<6048, 256, 0, stream>>>(vbuf, samp, aggb);
  k_gemmout<<<756, 256, 40960, stream>>>(aggb, WoutT, bout, out, img);
}

// Round 12
// 122.579 us; speedup vs baseline: 1.1128x; 1.1128x over previous
//
#include <hip/hip_runtime.h>

#define DEVINL __device__ __forceinline__

typedef __attribute__((ext_vector_type(4))) float f32x4;
typedef __attribute__((ext_vector_type(8))) short short8;

constexpr int kBN = 12, kC = 256, kH = 40, kW = 100;
constexpr int kNQ = kH * kW;      // 4000
constexpr int kM = kBN * kNQ;     // 48000

DEVINL float bflo(uint p) { union { uint i; float f; } v; v.i = p << 16; return v.f; }
DEVINL float bfhi(uint p) { union { uint i; float f; } v; v.i = p & 0xffff0000u; return v.f; }
DEVINL ushort f2bf(float f) {
  union { float f; uint i; } v; v.f = f;
  uint i = v.i;
  return (ushort)((i + 0x7fffu + ((i >> 16) & 1u)) >> 16);  // RNE
}
DEVINL uint pack2(float a, float b) { return (uint)f2bf(a) | ((uint)f2bf(b) << 16); }

DEVINL void mfma_bf16(f32x4& acc, short8 a, short8 b) {
  acc = __builtin_amdgcn_mfma_f32_16x16x32_bf16(a, b, acc, 0, 0, 0);
}

DEVINL void gload16(const ushort* g, char* lds) {
  __builtin_amdgcn_global_load_lds(
      (const __attribute__((address_space(1))) uint*)g,
      (__attribute__((address_space(3))) uint*)lds, 16, 0, 0);
}

DEVINL void acc8(float* acc, uint4 d, float wv) {
  acc[0] += wv * bflo(d.x); acc[1] += wv * bfhi(d.x);
  acc[2] += wv * bflo(d.y); acc[3] += wv * bfhi(d.y);
  acc[4] += wv * bflo(d.z); acc[5] += wv * bfhi(d.z);
  acc[6] += wv * bflo(d.w); acc[7] += wv * bfhi(d.w);
}

// ---------------- K0: all 4 weight transposes in one launch ------------------
__global__ __launch_bounds__(256) void k_wt_all(const float* __restrict__ Wv,
                                                const float* __restrict__ Woff,
                                                const float* __restrict__ Wattn,
                                                const float* __restrict__ Wout,
                                                ushort* __restrict__ WvT,
                                                ushort* __restrict__ WoffT,
                                                ushort* __restrict__ WattnT,
                                                ushort* __restrict__ WoutT) {
  int idx = blockIdx.x * 256 + threadIdx.x;
  const float* W; ushort* WT; int N, base;
  if (idx < 65536)       { W = Wv;    WT = WvT;    N = 256; base = 0; }
  else if (idx < 81920)  { W = Woff;  WT = WoffT;  N = 64;  base = 65536; }
  else if (idx < 90112)  { W = Wattn; WT = WattnT; N = 32;  base = 81920; }
  else if (idx < 155648) { W = Wout;  WT = WoutT;  N = 256; base = 90112; }
  else return;
  int i = idx - base;
  int n = i >> 8, k = i & 255;       // K = 256 for all
  WT[i] = f2bf(W[k * N + n]);
}

// ---------------- K1: img NCHW f32 -> feat [b][q][c] bf16 --------------------
// Store side vectorized: 2 x uint4 (8 bf16) per thread instead of 16 x ushort.
__global__ __launch_bounds__(256) void k_transpose(const float* __restrict__ img,
                                                   ushort* __restrict__ feat) {
  __shared__ ushort tile[64][66];
  int b = blockIdx.z, c0 = blockIdx.y * 64, q0 = blockIdx.x * 64;
  int t = threadIdx.x;
  int ql = t & 63, cl = t >> 6;
#pragma unroll
  for (int i = 0; i < 16; ++i) {
    int c = cl + i * 4, q = q0 + ql;
    float v = (q < kNQ) ? img[(size_t)(b * kC + c0 + c) * kNQ + q] : 0.f;
    tile[c][ql] = f2bf(v);
  }
  __syncthreads();
#pragma unroll
  for (int i = 0; i < 2; ++i) {
    int idx = t + i * 256;
    int qlo = idx >> 3, cg = idx & 7;     // 64 q x 8 c-groups (of 8)
    int q = q0 + qlo;
    if (q < kNQ) {
      ushort tmp[8];
#pragma unroll
      for (int j = 0; j < 8; ++j) tmp[j] = tile[cg * 8 + j][qlo];
      *(uint4*)(feat + ((size_t)b * kNQ + q) * kC + c0 + cg * 8) = *(uint4*)tmp;
    }
  }
}

// ---------------- K2: BEV warp: bilinear(feat, grid) -> warped bf16 ----------
__global__ __launch_bounds__(256) void k_warp(const ushort* __restrict__ feat,
                                              const float* __restrict__ grid,
                                              ushort* __restrict__ warped) {
  int orig = blockIdx.x;
  int n = (orig & 7) * 750 + (orig >> 3);     // bijective, 6000 = 8*750
  int t = threadIdx.x;
  int ql = t >> 5, g = t & 31;                // 8 q per block, 32 lanes per q
  int gq = n * 8 + ql;
  int b = gq / kNQ;
  float gx = grid[(size_t)gq * 2 + 0] * kW - 0.5f;
  float gy = grid[(size_t)gq * 2 + 1] * kH - 0.5f;
  float x0f = floorf(gx), y0f = floorf(gy);
  int x0 = (int)x0f, y0 = (int)y0f;
  float wx = gx - x0f, wy = gy - y0f;
  float acc[8];
#pragma unroll
  for (int i = 0; i < 8; ++i) acc[i] = 0.f;
  const ushort* fb = feat + (size_t)b * kNQ * kC + g * 8;
#pragma unroll
  for (int ty = 0; ty < 2; ++ty) {
    int iy = y0 + ty;
    if (iy < 0 || iy >= kH) continue;
    float wyv = ty ? wy : 1.f - wy;
#pragma unroll
    for (int tx = 0; tx < 2; ++tx) {
      int ix = x0 + tx;
      if (ix < 0 || ix >= kW) continue;
      float wv = wyv * (tx ? wx : 1.f - wx);
      uint4 d = *(const uint4*)(fb + (size_t)(iy * kW + ix) * kC);
      acc8(acc, d, wv);
    }
  }
  uint o[4] = {pack2(acc[0], acc[1]), pack2(acc[2], acc[3]),
               pack2(acc[4], acc[5]), pack2(acc[6], acc[7])};
  *(uint4*)(warped + (size_t)gq * kC + g * 8) = *(uint4*)o;
}

// ---------------- K3/K6: MFMA GEMM v4: BM=64, BN=256, BK=32 ------------------
// Counted-vmcnt double-buffered pipeline (5 uniform loads/thread/step).
template <int EPI>
__global__ __launch_bounds__(256) void k_gemm256(const ushort* __restrict__ A,
                                                 const ushort* __restrict__ BT,
                                                 const float* __restrict__ bias,
                                                 ushort* __restrict__ Obf,
                                                 float* __restrict__ Ofp,
                                                 const float* __restrict__ resid) {
  extern __shared__ char smem[];
  const int t = threadIdx.x, wave = t >> 6, lane = t & 63;
  const int l15 = lane & 15, l4 = lane >> 4;
  const int b = blockIdx.x / 63, mb = blockIdx.x % 63;
  const int q0 = mb * 64;
  const int nrows = (kNQ - q0 < 64) ? (kNQ - q0) : 64;
  const int n0w = wave * 64;
  const int ra = t >> 2, ca = t & 3;
  const int rac = (ra < nrows) ? ra : (nrows - 1);   // clamp: uniform 5 loads
  const int sca = ca ^ ((ra >> 1) & 3);
  const ushort* gA = A + ((size_t)b * kNQ + q0 + rac) * 256 + sca * 8;
  const ushort* gB = BT + (size_t)ra * 256 + sca * 8;

  f32x4 acc[4][4];
#pragma unroll
  for (int i = 0; i < 4; ++i)
#pragma unroll
    for (int j = 0; j < 4; ++j) acc[i][j] = (f32x4)0.f;

  auto STAGE = [&](int buf, int kk) {
    char* Asb = smem + buf * 20480;
    char* Bsb = Asb + 4096;
    gload16(gA + kk, Asb + t * 16);
#pragma unroll
    for (int i = 0; i < 4; ++i)
      gload16(gB + (size_t)i * 64 * 256 + kk, Bsb + (i * 256 + t) * 16);
  };

  STAGE(0, 0);
  int cur = 0;
#pragma unroll 1
  for (int step = 0; step < 8; ++step) {
    if (step < 7) {
      STAGE(cur ^ 1, (step + 1) * 32);
      asm volatile("s_waitcnt vmcnt(5)" ::: "memory");
    } else {
      asm volatile("s_waitcnt vmcnt(0)" ::: "memory");
    }
    __builtin_amdgcn_s_barrier();
    asm volatile("" ::: "memory");
    char* Asb = smem + cur * 20480;
    char* Bsb = Asb + 4096;
    short8 af[4], bf[4];
#pragma unroll
    for (int mf = 0; mf < 4; ++mf) {
      int r = mf * 16 + l15;
      int sl = l4 ^ ((r >> 1) & 3);
      af[mf] = *(const short8*)(Asb + r * 64 + sl * 16);
    }
#pragma unroll
    for (int nf = 0; nf < 4; ++nf) {
      int r = n0w + nf * 16 + l15;
      int sl = l4 ^ ((r >> 1) & 3);
      bf[nf] = *(const short8*)(Bsb + r * 64 + sl * 16);
    }
#pragma unroll
    for (int mf = 0; mf < 4; ++mf)
#pragma unroll
      for (int nf = 0; nf < 4; ++nf) mfma_bf16(acc[mf][nf], af[mf], bf[nf]);
    asm volatile("" ::: "memory");
    __builtin_amdgcn_s_barrier();
    cur ^= 1;
  }

  if (EPI == 0) {
#pragma unroll
    for (int mf = 0; mf < 4; ++mf) {
      if (mf * 16 >= nrows) continue;
      int q = q0 + mf * 16 + l4 * 4;
#pragma unroll
      for (int nf = 0; nf < 4; ++nf) {
        int col = n0w + nf * 16 + l15;
        float bv = bias[col];
        int h = col >> 5, ch = col & 31;
        ushort* dst = Obf + (size_t)(b * 8 + h) * kNQ * 32 + ch;
#pragma unroll
        for (int j = 0; j < 4; ++j)
          dst[(size_t)(q + j) * 32] = f2bf(acc[mf][nf][j] + bv);
      }
    }
  } else {
    // per-wave transpose scratch: [16 cols][68 rows] fp32 = 4352 B per wave
    float* Tw = (float*)(smem + wave * 4352);
#pragma unroll
    for (int nf = 0; nf < 4; ++nf) {
      float bv = bias[n0w + nf * 16 + l15];
#pragma unroll
      for (int mf = 0; mf < 4; ++mf)
#pragma unroll
        for (int j = 0; j < 4; ++j)
          Tw[l15 * 68 + mf * 16 + l4 * 4 + j] = acc[mf][nf][j] + bv;
      int c = l15, rs = l4 * 16;
      if (rs < nrows) {
        int col = n0w + nf * 16 + c;
        size_t gi = ((size_t)b * kC + col) * kNQ + q0 + rs;
#pragma unroll
        for (int k = 0; k < 4; ++k) {
          float4 tv = *(float4*)(&Tw[c * 68 + rs + k * 4]);
          float4 rv = *(const float4*)(resid + gi + k * 4);
          tv.x += rv.x; tv.y += rv.y; tv.z += rv.z; tv.w += rv.w;
          *(float4*)(Ofp + gi + k * 4) = tv;
        }
      }
    }
  }
}

// ---------------- K4: off+attn GEMM (BM=64, BN=96) counted-vmcnt + softmax ---
// Loads wave-uniform: waves 0-1 = 3/step (A,B0,B1), waves 2-3 = 2/step (A,B0).
// samp layout: [b][h][q][p] packed 12 B {sx, sy, w}
__global__ __launch_bounds__(256) void k_offattn(const ushort* __restrict__ A,
                                                 const ushort* __restrict__ WoffT,
                                                 const ushort* __restrict__ WattnT,
                                                 const float* __restrict__ boff,
                                                 const float* __restrict__ battn,
                                                 const float* __restrict__ refp,
                                                 float* __restrict__ samp) {
  extern __shared__ char smem[];
  float* T = (float*)smem;    // epilogue: [64][101] fp32 = 25856 B (aliases bufs)
  const int t = threadIdx.x, wave = t >> 6, lane = t & 63;
  const int l15 = lane & 15, l4 = lane >> 4;
  const int b = blockIdx.x / 63, mb = blockIdx.x % 63;
  const int q0 = mb * 64;
  const int nrows = (kNQ - q0 < 64) ? (kNQ - q0) : 64;
  const int wr = wave >> 1, wc = wave & 1;
  const int ra = t >> 2, ca = t & 3;
  const int rac = (ra < nrows) ? ra : (nrows - 1);   // clamp: uniform A load
  const int sca = ca ^ ((ra >> 1) & 3);
  const ushort* gA  = A + ((size_t)b * kNQ + q0 + rac) * 256 + sca * 8;
  const ushort* gB0 = WoffT + (size_t)ra * 256 + sca * 8;
  const ushort* gB1 = WattnT + (size_t)ra * 256 + sca * 8;  // t<128 (ra<32)

  f32x4 acc[2][3];
#pragma unroll
  for (int i = 0; i < 2; ++i)
#pragma unroll
    for (int j = 0; j < 3; ++j) acc[i][j] = (f32x4)0.f;

  auto STAGE = [&](int buf, int kk) {
    char* Asb = smem + buf * 10240;
    char* Bsb = Asb + 4096;
    gload16(gA + kk, Asb + t * 16);
    gload16(gB0 + kk, Bsb + t * 16);
    if (t < 128) gload16(gB1 + kk, Bsb + (256 + t) * 16);
  };

  STAGE(0, 0);
  int cur = 0;
#pragma unroll 1
  for (int step = 0; step < 8; ++step) {
    if (step < 7) {
      STAGE(cur ^ 1, (step + 1) * 32);
      if (wave < 2) asm volatile("s_waitcnt vmcnt(3)" ::: "memory");
      else          asm volatile("s_waitcnt vmcnt(2)" ::: "memory");
    } else {
      asm volatile("s_waitcnt vmcnt(0)" ::: "memory");
    }
    __builtin_amdgcn_s_barrier();
    asm volatile("" ::: "memory");
    char* Asb = smem + cur * 10240;
    char* Bsb = Asb + 4096;
    short8 af[2], bf[3];
#pragma unroll
    for (int mf = 0; mf < 2; ++mf) {
      int r = wr * 32 + mf * 16 + l15;
      int sl = l4 ^ ((r >> 1) & 3);
      af[mf] = *(const short8*)(Asb + r * 64 + sl * 16);
    }
#pragma unroll
    for (int nf = 0; nf < 3; ++nf) {
      int r = wc * 48 + nf * 16 + l15;
      int sl = l4 ^ ((r >> 1) & 3);
      bf[nf] = *(const short8*)(Bsb + r * 64 + sl * 16);
    }
#pragma unroll
    for (int mf = 0; mf < 2; ++mf)
#pragma unroll
      for (int nf = 0; nf < 3; ++nf) mfma_bf16(acc[mf][nf], af[mf], bf[nf]);
    asm volatile("" ::: "memory");
    __builtin_amdgcn_s_barrier();
    cur ^= 1;
  }

#pragma unroll
  for (int nf = 0; nf < 3; ++nf) {
    int col = wc * 48 + nf * 16 + l15;
    float bv = (col < 64) ? boff[col] : battn[col - 64];
#pragma unroll
    for (int mf = 0; mf < 2; ++mf)
#pragma unroll
      for (int j = 0; j < 4; ++j) {
        int row = wr * 32 + mf * 16 + l4 * 4 + j;
        T[row * 101 + col] = acc[mf][nf][j] + bv;
      }
  }
  __syncthreads();
  int row = t >> 2;
  if (row < nrows) {
    int q = q0 + row;
    float refx = refp[((size_t)b * kNQ + q) * 2 + 0] * kW - 0.5f;
    float refy = refp[((size_t)b * kNQ + q) * 2 + 1] * kH - 0.5f;
#pragma unroll
    for (int hi2 = 0; hi2 < 2; ++hi2) {
      int h = (t & 3) + hi2 * 4;
      float sx[4], sy[4], lg[4];
#pragma unroll
      for (int p = 0; p < 4; ++p) {
        sx[p] = refx + T[row * 101 + h * 8 + p * 2 + 0];
        sy[p] = refy + T[row * 101 + h * 8 + p * 2 + 1];
        lg[p] = T[row * 101 + 64 + h * 4 + p];
      }
      float mx = fmaxf(fmaxf(lg[0], lg[1]), fmaxf(lg[2], lg[3]));
      float e[4], s = 0.f;
#pragma unroll
      for (int p = 0; p < 4; ++p) { e[p] = __expf(lg[p] - mx); s += e[p]; }
      float inv = 1.f / s;
      float* dst = samp + (((size_t)(b * 8 + h) * kNQ + q) * 4) * 3;
#pragma unroll
      for (int p = 0; p < 4; ++p) {
        dst[p * 3 + 0] = sx[p];
        dst[p * 3 + 1] = sy[p];
        dst[p * 3 + 2] = e[p] * inv;
      }
    }
  }
}

// ---------------- K5: deformable sampling + attention aggregate --------------
__global__ __launch_bounds__(256) void k_sample(const ushort* __restrict__ v,
                                                const float* __restrict__ samp,
                                                ushort* __restrict__ agg) {
  int orig = blockIdx.x;
  int n = (orig & 7) * 756 + (orig >> 3);      // bijective, 6048 = 8*756
  int plane = n / 63, chunk = n - plane * 63;  // 96 planes x 63 chunks
  int t = threadIdx.x;
  int ql = t >> 2, g = t & 3;                  // 64 q per block, 4 lanes per q
  int q = chunk * 64 + ql;
  if (q >= kNQ) return;
  int b = plane >> 3, h = plane & 7;
  const ushort* pv = v + (size_t)plane * kNQ * 32 + g * 8;
  const int lane = t & 63, gbase = lane & ~3;

  const float* sp = samp + (((size_t)plane * kNQ + q) * 4 + g) * 3;
  float myx = sp[0], myy = sp[1], myw = sp[2];   // lane g owns point g
  float acc[8];
#pragma unroll
  for (int i = 0; i < 8; ++i) acc[i] = 0.f;
#pragma unroll
  for (int p = 0; p < 4; ++p) {
    float sxp = __shfl(myx, gbase + p);
    float syp = __shfl(myy, gbase + p);
    float wp  = __shfl(myw, gbase + p);
    float x0f = floorf(sxp), y0f = floorf(syp);
    int x0 = (int)x0f, y0 = (int)y0f;
    float wx = sxp - x0f, wy = syp - y0f;
#pragma unroll
    for (int ty = 0; ty < 2; ++ty) {
      int iy = y0 + ty;
      if (iy < 0 || iy >= kH) continue;
      float wyv = ty ? wy : 1.f - wy;
#pragma unroll
      for (int tx = 0; tx < 2; ++tx) {
        int ix = x0 + tx;
        if (ix < 0 || ix >= kW) continue;
        float wv = wp * wyv * (tx ? wx : 1.f - wx);
        uint4 d = *(const uint4*)(pv + (size_t)(iy * kW + ix) * 32);
        acc8(acc, d, wv);
      }
    }
  }
  uint o[4] = {pack2(acc[0], acc[1]), pack2(acc[2], acc[3]),
               pack2(acc[4], acc[5]), pack2(acc[6], acc[7])};
  *(uint4*)(agg + ((size_t)b * kNQ + q) * kC + h * 32 + g * 8) = *(uint4*)o;
}

extern "C" void kernel_launch(void* const* d_in, const int* in_sizes, int n_in,
                              void* d_out, int out_size, void* d_ws, size_t ws_size,
                              hipStream_t stream) {
  const float* img   = (const float*)d_in[0];
  const float* grid  = (const float*)d_in[1];
  const float* refp  = (const float*)d_in[2];
  const float* Wv    = (const float*)d_in[3];
  const float* bv    = (const float*)d_in[4];
  const float* Woff  = (const float*)d_in[5];
  const float* boff  = (const float*)d_in[6];
  const float* Wattn = (const float*)d_in[7];
  const float* battn = (const float*)d_in[8];
  const float* Wout  = (const float*)d_in[9];
  const float* bout  = (const float*)d_in[10];
  float* out = (float*)d_out;

  char* ws = (char*)d_ws;
  const size_t SZ = (size_t)kM * kC * 2;  // 24.576 MB per bf16 [M][C] buffer
  ushort* feat   = (ushort*)(ws);
  ushort* warped = (ushort*)(ws + SZ);
  ushort* vbuf   = (ushort*)(ws + 2 * SZ);           // [b][h][q][32] head-major
  float*  samp   = (float*)(ws + 3 * SZ);            // [b][h][q][p]{x,y,w} 18.4 MB
  ushort* WvT    = (ushort*)(ws + 4 * SZ);
  ushort* WoffT  = (ushort*)(ws + 4 * SZ + 131072);
  ushort* WattnT = (ushort*)(ws + 4 * SZ + 131072 + 32768);
  ushort* WoutT  = (ushort*)(ws + 4 * SZ + 131072 + 32768 + 16384);
  ushort* aggb   = warped;  // warped is dead after gemm<0>; reuse for agg

  k_wt_all<<<608, 256, 0, stream>>>(Wv, Woff, Wattn, Wout, WvT, WoffT, WattnT, WoutT);
  k_transpose<<<dim3(63, 4, 12), 256, 0, stream>>>(img, feat);
  k_warp<<<6000, 256, 0, stream>>>(feat, grid, warped);
  k_gemm256<0><<<756, 256, 40960, stream>>>(warped, WvT, bv, vbuf, nullptr, nullptr);
  k_offattn<<<756, 256, 25856, stream>>>(feat, WoffT, WattnT, boff, battn, refp, samp);
  k_sample<<<6048, 256, 0, stream>>>(vbuf, samp, aggb);
  k_gemm256<1><<<756, 256, 40960, stream>>>(aggb, WoutT, bout, nullptr, out, img);
}

// Round 14
// 114.982 us; speedup vs baseline: 1.1863x; 1.0661x over previous
//
#include <hip/hip_runtime.h>

#define DEVINL __device__ __forceinline__

typedef __attribute__((ext_vector_type(4))) float f32x4;
typedef __attribute__((ext_vector_type(8))) short short8;

constexpr int kBN = 12, kC = 256, kH = 40, kW = 100;
constexpr int kNQ = kH * kW;      // 4000
constexpr int kM = kBN * kNQ;     // 48000

DEVINL float bflo(uint p) { union { uint i; float f; } v; v.i = p << 16; return v.f; }
DEVINL float bfhi(uint p) { union { uint i; float f; } v; v.i = p & 0xffff0000u; return v.f; }
DEVINL ushort f2bf(float f) {
  union { float f; uint i; } v; v.f = f;
  uint i = v.i;
  return (ushort)((i + 0x7fffu + ((i >> 16) & 1u)) >> 16);  // RNE
}
DEVINL uint pack2(float a, float b) { return (uint)f2bf(a) | ((uint)f2bf(b) << 16); }

DEVINL void mfma_bf16(f32x4& acc, short8 a, short8 b) {
  acc = __builtin_amdgcn_mfma_f32_16x16x32_bf16(a, b, acc, 0, 0, 0);
}

DEVINL void gload16(const ushort* g, char* lds) {
  __builtin_amdgcn_global_load_lds(
      (const __attribute__((address_space(1))) uint*)g,
      (__attribute__((address_space(3))) uint*)lds, 16, 0, 0);
}

DEVINL void acc8(float* acc, uint4 d, float wv) {
  acc[0] += wv * bflo(d.x); acc[1] += wv * bfhi(d.x);
  acc[2] += wv * bflo(d.y); acc[3] += wv * bfhi(d.y);
  acc[4] += wv * bflo(d.z); acc[5] += wv * bfhi(d.z);
  acc[6] += wv * bflo(d.w); acc[7] += wv * bfhi(d.w);
}

// ---------------- K1: img transpose (blocks 0..3023) + weight prep (3024+) --
__global__ __launch_bounds__(256) void k_prep(const float* __restrict__ img,
                                              ushort* __restrict__ feat,
                                              const float* __restrict__ Wv,
                                              const float* __restrict__ Woff,
                                              const float* __restrict__ Wattn,
                                              const float* __restrict__ Wout,
                                              ushort* __restrict__ WvT,
                                              ushort* __restrict__ WoffT,
                                              ushort* __restrict__ WattnT,
                                              ushort* __restrict__ WoutT) {
  __shared__ ushort tile[64][66];
  int bx = blockIdx.x, t = threadIdx.x;
  if (bx < 3024) {
    int qb = bx % 63, cb = (bx / 63) & 3, b = bx / 252;
    int c0 = cb * 64, q0 = qb * 64;
    int ql = t & 63, cl = t >> 6;
#pragma unroll
    for (int i = 0; i < 16; ++i) {
      int c = cl + i * 4, q = q0 + ql;
      float v = (q < kNQ) ? img[(size_t)(b * kC + c0 + c) * kNQ + q] : 0.f;
      tile[c][ql] = f2bf(v);
    }
    __syncthreads();
#pragma unroll
    for (int i = 0; i < 2; ++i) {
      int idx = t + i * 256;
      int qlo = idx >> 3, cg = idx & 7;
      int q = q0 + qlo;
      if (q < kNQ) {
        ushort tmp[8];
#pragma unroll
        for (int j = 0; j < 8; ++j) tmp[j] = tile[cg * 8 + j][qlo];
        *(uint4*)(feat + ((size_t)b * kNQ + q) * kC + c0 + cg * 8) = *(uint4*)tmp;
      }
    }
  } else {
    int idx = (bx - 3024) * 256 + t;
    const float* W; ushort* WT; int N, base;
    if (idx < 65536)       { W = Wv;    WT = WvT;    N = 256; base = 0; }
    else if (idx < 81920)  { W = Woff;  WT = WoffT;  N = 64;  base = 65536; }
    else if (idx < 90112)  { W = Wattn; WT = WattnT; N = 32;  base = 81920; }
    else if (idx < 155648) { W = Wout;  WT = WoutT;  N = 256; base = 90112; }
    else return;
    int i = idx - base;
    int n = i >> 8, k = i & 255;
    WT[i] = f2bf(W[k * N + n]);
  }
}

// ---------------- K2: MERGED warp (blocks 756..6755) + offattn (0..755) ------
// Independent work co-scheduled in one launch: gather-latency-bound warp waves
// overlap with MFMA-bound offattn waves on the same CUs (separate pipes).
// samp layout: [b][h][q][p] packed 12 B {sx, sy, w}
__global__ __launch_bounds__(256) void k_warp_offattn(const ushort* __restrict__ feat,
                                                      const float* __restrict__ grid,
                                                      ushort* __restrict__ warped,
                                                      const ushort* __restrict__ WoffT,
                                                      const ushort* __restrict__ WattnT,
                                                      const float* __restrict__ boff,
                                                      const float* __restrict__ battn,
                                                      const float* __restrict__ refp,
                                                      float* __restrict__ samp) {
  extern __shared__ char smem[];
  const int t = threadIdx.x;
  int bx = blockIdx.x;

  if (bx >= 756) {
    // ---------------- warp path ----------------
    int orig = bx - 756;
    int n = (orig & 7) * 750 + (orig >> 3);   // bijective, 6000 = 8*750
    int ql = t >> 5, g = t & 31;              // 8 q per block, 32 lanes per q
    int gq = n * 8 + ql;
    int b = gq / kNQ;
    float gx = grid[(size_t)gq * 2 + 0] * kW - 0.5f;
    float gy = grid[(size_t)gq * 2 + 1] * kH - 0.5f;
    float x0f = floorf(gx), y0f = floorf(gy);
    int x0 = (int)x0f, y0 = (int)y0f;
    float wx = gx - x0f, wy = gy - y0f;
    float acc[8];
#pragma unroll
    for (int i = 0; i < 8; ++i) acc[i] = 0.f;
    const ushort* fb = feat + (size_t)b * kNQ * kC + g * 8;
#pragma unroll
    for (int ty = 0; ty < 2; ++ty) {
      int iy = y0 + ty;
      if (iy < 0 || iy >= kH) continue;
      float wyv = ty ? wy : 1.f - wy;
#pragma unroll
      for (int tx = 0; tx < 2; ++tx) {
        int ix = x0 + tx;
        if (ix < 0 || ix >= kW) continue;
        float wv = wyv * (tx ? wx : 1.f - wx);
        uint4 d = *(const uint4*)(fb + (size_t)(iy * kW + ix) * kC);
        acc8(acc, d, wv);
      }
    }
    uint o[4] = {pack2(acc[0], acc[1]), pack2(acc[2], acc[3]),
                 pack2(acc[4], acc[5]), pack2(acc[6], acc[7])};
    *(uint4*)(warped + (size_t)gq * kC + g * 8) = *(uint4*)o;
    return;
  }

  // ---------------- offattn path (counted-vmcnt dbuf GEMM + softmax) --------
  float* T = (float*)smem;    // epilogue [64][101] fp32 (aliases staging bufs)
  const int wave = t >> 6, lane = t & 63;
  const int l15 = lane & 15, l4 = lane >> 4;
  const int b = bx / 63, mb = bx % 63;
  const int q0 = mb * 64;
  const int nrows = (kNQ - q0 < 64) ? (kNQ - q0) : 64;
  const int wr = wave >> 1, wc = wave & 1;
  const int ra = t >> 2, ca = t & 3;
  const int rac = (ra < nrows) ? ra : (nrows - 1);
  const int sca = ca ^ ((ra >> 1) & 3);
  const ushort* gA  = feat + ((size_t)b * kNQ + q0 + rac) * 256 + sca * 8;
  const ushort* gB0 = WoffT + (size_t)ra * 256 + sca * 8;
  const ushort* gB1 = WattnT + (size_t)ra * 256 + sca * 8;  // t<128 (ra<32)

  f32x4 acc[2][3];
#pragma unroll
  for (int i = 0; i < 2; ++i)
#pragma unroll
    for (int j = 0; j < 3; ++j) acc[i][j] = (f32x4)0.f;

  auto STAGE = [&](int buf, int kk) {
    char* Asb = smem + buf * 10240;
    char* Bsb = Asb + 4096;
    gload16(gA + kk, Asb + t * 16);
    gload16(gB0 + kk, Bsb + t * 16);
    if (t < 128) gload16(gB1 + kk, Bsb + (256 + t) * 16);
  };

  STAGE(0, 0);
  int cur = 0;
#pragma unroll 1
  for (int step = 0; step < 8; ++step) {
    if (step < 7) {
      STAGE(cur ^ 1, (step + 1) * 32);
      if (wave < 2) asm volatile("s_waitcnt vmcnt(3)" ::: "memory");
      else          asm volatile("s_waitcnt vmcnt(2)" ::: "memory");
    } else {
      asm volatile("s_waitcnt vmcnt(0)" ::: "memory");
    }
    __builtin_amdgcn_s_barrier();
    asm volatile("" ::: "memory");
    char* Asb = smem + cur * 10240;
    char* Bsb = Asb + 4096;
    short8 af[2], bf[3];
#pragma unroll
    for (int mf = 0; mf < 2; ++mf) {
      int r = wr * 32 + mf * 16 + l15;
      int sl = l4 ^ ((r >> 1) & 3);
      af[mf] = *(const short8*)(Asb + r * 64 + sl * 16);
    }
#pragma unroll
    for (int nf = 0; nf < 3; ++nf) {
      int r = wc * 48 + nf * 16 + l15;
      int sl = l4 ^ ((r >> 1) & 3);
      bf[nf] = *(const short8*)(Bsb + r * 64 + sl * 16);
    }
#pragma unroll
    for (int mf = 0; mf < 2; ++mf)
#pragma unroll
      for (int nf = 0; nf < 3; ++nf) mfma_bf16(acc[mf][nf], af[mf], bf[nf]);
    asm volatile("" ::: "memory");
    __builtin_amdgcn_s_barrier();
    cur ^= 1;
  }

#pragma unroll
  for (int nf = 0; nf < 3; ++nf) {
    int col = wc * 48 + nf * 16 + l15;
    float bv = (col < 64) ? boff[col] : battn[col - 64];
#pragma unroll
    for (int mf = 0; mf < 2; ++mf)
#pragma unroll
      for (int j = 0; j < 4; ++j) {
        int row = wr * 32 + mf * 16 + l4 * 4 + j;
        T[row * 101 + col] = acc[mf][nf][j] + bv;
      }
  }
  __syncthreads();
  int row = t >> 2;
  if (row < nrows) {
    int q = q0 + row;
    float refx = refp[((size_t)b * kNQ + q) * 2 + 0] * kW - 0.5f;
    float refy = refp[((size_t)b * kNQ + q) * 2 + 1] * kH - 0.5f;
#pragma unroll
    for (int hi2 = 0; hi2 < 2; ++hi2) {
      int h = (t & 3) + hi2 * 4;
      float sx[4], sy[4], lg[4];
#pragma unroll
      for (int p = 0; p < 4; ++p) {
        sx[p] = refx + T[row * 101 + h * 8 + p * 2 + 0];
        sy[p] = refy + T[row * 101 + h * 8 + p * 2 + 1];
        lg[p] = T[row * 101 + 64 + h * 4 + p];
      }
      float mx = fmaxf(fmaxf(lg[0], lg[1]), fmaxf(lg[2], lg[3]));
      float e[4], s = 0.f;
#pragma unroll
      for (int p = 0; p < 4; ++p) { e[p] = __expf(lg[p] - mx); s += e[p]; }
      float inv = 1.f / s;
      float* dst = samp + (((size_t)(b * 8 + h) * kNQ + q) * 4) * 3;
#pragma unroll
      for (int p = 0; p < 4; ++p) {
        dst[p * 3 + 0] = sx[p];
        dst[p * 3 + 1] = sy[p];
        dst[p * 3 + 2] = e[p] * inv;
      }
    }
  }
}

// ---------------- K3: MFMA GEMM v (BM=64, BN=256), counted-vmcnt dbuf --------
__global__ __launch_bounds__(256) void k_gemmv(const ushort* __restrict__ A,
                                               const ushort* __restrict__ BT,
                                               const float* __restrict__ bias,
                                               ushort* __restrict__ Obf) {
  extern __shared__ char smem[];
  const int t = threadIdx.x, wave = t >> 6, lane = t & 63;
  const int l15 = lane & 15, l4 = lane >> 4;
  const int b = blockIdx.x / 63, mb = blockIdx.x % 63;
  const int q0 = mb * 64;
  const int nrows = (kNQ - q0 < 64) ? (kNQ - q0) : 64;
  const int n0w = wave * 64;
  const int ra = t >> 2, ca = t & 3;
  const int rac = (ra < nrows) ? ra : (nrows - 1);
  const int sca = ca ^ ((ra >> 1) & 3);
  const ushort* gA = A + ((size_t)b * kNQ + q0 + rac) * 256 + sca * 8;
  const ushort* gB = BT + (size_t)ra * 256 + sca * 8;

  f32x4 acc[4][4];
#pragma unroll
  for (int i = 0; i < 4; ++i)
#pragma unroll
    for (int j = 0; j < 4; ++j) acc[i][j] = (f32x4)0.f;

  auto STAGE = [&](int buf, int kk) {
    char* Asb = smem + buf * 20480;
    char* Bsb = Asb + 4096;
    gload16(gA + kk, Asb + t * 16);
#pragma unroll
    for (int i = 0; i < 4; ++i)
      gload16(gB + (size_t)i * 64 * 256 + kk, Bsb + (i * 256 + t) * 16);
  };

  STAGE(0, 0);
  int cur = 0;
#pragma unroll 1
  for (int step = 0; step < 8; ++step) {
    if (step < 7) {
      STAGE(cur ^ 1, (step + 1) * 32);
      asm volatile("s_waitcnt vmcnt(5)" ::: "memory");
    } else {
      asm volatile("s_waitcnt vmcnt(0)" ::: "memory");
    }
    __builtin_amdgcn_s_barrier();
    asm volatile("" ::: "memory");
    char* Asb = smem + cur * 20480;
    char* Bsb = Asb + 4096;
    short8 af[4], bf[4];
#pragma unroll
    for (int mf = 0; mf < 4; ++mf) {
      int r = mf * 16 + l15;
      int sl = l4 ^ ((r >> 1) & 3);
      af[mf] = *(const short8*)(Asb + r * 64 + sl * 16);
    }
#pragma unroll
    for (int nf = 0; nf < 4; ++nf) {
      int r = n0w + nf * 16 + l15;
      int sl = l4 ^ ((r >> 1) & 3);
      bf[nf] = *(const short8*)(Bsb + r * 64 + sl * 16);
    }
#pragma unroll
    for (int mf = 0; mf < 4; ++mf)
#pragma unroll
      for (int nf = 0; nf < 4; ++nf) mfma_bf16(acc[mf][nf], af[mf], bf[nf]);
    asm volatile("" ::: "memory");
    __builtin_amdgcn_s_barrier();
    cur ^= 1;
  }

#pragma unroll
  for (int mf = 0; mf < 4; ++mf) {
    if (mf * 16 >= nrows) continue;
    int q = q0 + mf * 16 + l4 * 4;
#pragma unroll
    for (int nf = 0; nf < 4; ++nf) {
      int col = n0w + nf * 16 + l15;
      float bv = bias[col];
      int h = col >> 5, ch = col & 31;
      ushort* dst = Obf + (size_t)(b * 8 + h) * kNQ * 32 + ch;
#pragma unroll
      for (int j = 0; j < 4; ++j)
        dst[(size_t)(q + j) * 32] = f2bf(acc[mf][nf][j] + bv);
    }
  }
}

// ---------------- K4: deformable sampling + attention aggregate --------------
__global__ __launch_bounds__(256) void k_sample(const ushort* __restrict__ v,
                                                const float* __restrict__ samp,
                                                ushort* __restrict__ agg) {
  int orig = blockIdx.x;
  int n = (orig & 7) * 756 + (orig >> 3);      // bijective, 6048 = 8*756
  int plane = n / 63, chunk = n - plane * 63;  // 96 planes x 63 chunks
  int t = threadIdx.x;
  int ql = t >> 2, g = t & 3;                  // 64 q per block, 4 lanes per q
  int q = chunk * 64 + ql;
  if (q >= kNQ) return;
  int b = plane >> 3, h = plane & 7;
  const ushort* pv = v + (size_t)plane * kNQ * 32 + g * 8;
  const int lane = t & 63, gbase = lane & ~3;

  const float* sp = samp + (((size_t)plane * kNQ + q) * 4 + g) * 3;
  float myx = sp[0], myy = sp[1], myw = sp[2];   // lane g owns point g
  float acc[8];
#pragma unroll
  for (int i = 0; i < 8; ++i) acc[i] = 0.f;
#pragma unroll
  for (int p = 0; p < 4; ++p) {
    float sxp = __shfl(myx, gbase + p);
    float syp = __shfl(myy, gbase + p);
    float wp  = __shfl(myw, gbase + p);
    float x0f = floorf(sxp), y0f = floorf(syp);
    int x0 = (int)x0f, y0 = (int)y0f;
    float wx = sxp - x0f, wy = syp - y0f;
#pragma unroll
    for (int ty = 0; ty < 2; ++ty) {
      int iy = y0 + ty;
      if (iy < 0 || iy >= kH) continue;
      float wyv = ty ? wy : 1.f - wy;
#pragma unroll
      for (int tx = 0; tx < 2; ++tx) {
        int ix = x0 + tx;
        if (ix < 0 || ix >= kW) continue;
        float wv = wp * wyv * (tx ? wx : 1.f - wx);
        uint4 d = *(const uint4*)(pv + (size_t)(iy * kW + ix) * 32);
        acc8(acc, d, wv);
      }
    }
  }
  uint o[4] = {pack2(acc[0], acc[1]), pack2(acc[2], acc[3]),
               pack2(acc[4], acc[5]), pack2(acc[6], acc[7])};
  *(uint4*)(agg + ((size_t)b * kNQ + q) * kC + h * 32 + g * 8) = *(uint4*)o;
}

// ---------------- K5: MFMA GEMM out, bf16 residual from feat -----------------
__global__ __launch_bounds__(256) void k_gemmout(const ushort* __restrict__ A,
                                                 const ushort* __restrict__ BT,
                                                 const float* __restrict__ bias,
                                                 float* __restrict__ Ofp,
                                                 const ushort* __restrict__ feat) {
  extern __shared__ char smem[];
  const int t = threadIdx.x, wave = t >> 6, lane = t & 63;
  const int l15 = lane & 15, l4 = lane >> 4;
  const int b = blockIdx.x / 63, mb = blockIdx.x % 63;
  const int q0 = mb * 64;
  const int nrows = (kNQ - q0 < 64) ? (kNQ - q0) : 64;
  const int n0w = wave * 64;
  const int ra = t >> 2, ca = t & 3;
  const int rac = (ra < nrows) ? ra : (nrows - 1);
  const int sca = ca ^ ((ra >> 1) & 3);
  const ushort* gA = A + ((size_t)b * kNQ + q0 + rac) * 256 + sca * 8;
  const ushort* gB = BT + (size_t)ra * 256 + sca * 8;

  f32x4 acc[4][4];
#pragma unroll
  for (int i = 0; i < 4; ++i)
#pragma unroll
    for (int j = 0; j < 4; ++j) acc[i][j] = (f32x4)0.f;

  auto STAGE = [&](int buf, int kk) {
    char* Asb = smem + buf * 20480;
    char* Bsb = Asb + 4096;
    gload16(gA + kk, Asb + t * 16);
#pragma unroll
    for (int i = 0; i < 4; ++i)
      gload16(gB + (size_t)i * 64 * 256 + kk, Bsb + (i * 256 + t) * 16);
  };

  STAGE(0, 0);
  int cur = 0;
#pragma unroll 1
  for (int step = 0; step < 8; ++step) {
    if (step < 7) {
      STAGE(cur ^ 1, (step + 1) * 32);
      asm volatile("s_waitcnt vmcnt(5)" ::: "memory");
    } else {
      asm volatile("s_waitcnt vmcnt(0)" ::: "memory");
    }
    __builtin_amdgcn_s_barrier();
    asm volatile("" ::: "memory");
    char* Asb = smem + cur * 20480;
    char* Bsb = Asb + 4096;
    short8 af[4], bf[4];
#pragma unroll
    for (int mf = 0; mf < 4; ++mf) {
      int r = mf * 16 + l15;
      int sl = l4 ^ ((r >> 1) & 3);
      af[mf] = *(const short8*)(Asb + r * 64 + sl * 16);
    }
#pragma unroll
    for (int nf = 0; nf < 4; ++nf) {
      int r = n0w + nf * 16 + l15;
      int sl = l4 ^ ((r >> 1) & 3);
      bf[nf] = *(const short8*)(Bsb + r * 64 + sl * 16);
    }
#pragma unroll
    for (int mf = 0; mf < 4; ++mf)
#pragma unroll
      for (int nf = 0; nf < 4; ++nf) mfma_bf16(acc[mf][nf], af[mf], bf[nf]);
    asm volatile("" ::: "memory");
    __builtin_amdgcn_s_barrier();
    cur ^= 1;
  }

  // epilogue: per-wave LDS transpose + bf16 residual (from feat) + NCHW store
  float* Tw = (float*)(smem + wave * 4352);   // [16 cols][68 rows] fp32
#pragma unroll
  for (int nf = 0; nf < 4; ++nf) {
    float bv = bias[n0w + nf * 16 + l15];
#pragma unroll
    for (int mf = 0; mf < 4; ++mf)
#pragma unroll
      for (int j = 0; j < 4; ++j)
        Tw[l15 * 68 + mf * 16 + l4 * 4 + j] = acc[mf][nf][j] + bv;
    int c = l15, rs = l4 * 16;
    if (rs < nrows) {
      int col = n0w + nf * 16 + c;
      size_t gi = ((size_t)b * kC + col) * kNQ + q0 + rs;
      const ushort* fr = feat + ((size_t)b * kNQ + q0 + rs) * kC + col;
#pragma unroll
      for (int k = 0; k < 4; ++k) {
        float4 tv = *(float4*)(&Tw[c * 68 + rs + k * 4]);
        tv.x += bflo(fr[(size_t)(k * 4 + 0) * kC]);
        tv.y += bflo(fr[(size_t)(k * 4 + 1) * kC]);
        tv.z += bflo(fr[(size_t)(k * 4 + 2) * kC]);
        tv.w += bflo(fr[(size_t)(k * 4 + 3) * kC]);
        *(float4*)(Ofp + gi + k * 4) = tv;
      }
    }
  }
}

extern "C" void kernel_launch(void* const* d_in, const int* in_sizes, int n_in,
                              void* d_out, int out_size, void* d_ws, size_t ws_size,
                              hipStream_t stream) {
  const float* img   = (const float*)d_in[0];
  const float* grid  = (const float*)d_in[1];
  const float* refp  = (const float*)d_in[2];
  const float* Wv    = (const float*)d_in[3];
  const float* bv    = (const float*)d_in[4];
  const float* Woff  = (const float*)d_in[5];
  const float* boff  = (const float*)d_in[6];
  const float* Wattn = (const float*)d_in[7];
  const float* battn = (const float*)d_in[8];
  const float* Wout  = (const float*)d_in[9];
  const float* bout  = (const float*)d_in[10];
  float* out = (float*)d_out;

  char* ws = (char*)d_ws;
  const size_t SZ = (size_t)kM * kC * 2;  // 24.576 MB per bf16 [M][C] buffer
  ushort* feat   = (ushort*)(ws);
  ushort* warped = (ushort*)(ws + SZ);
  ushort* vbuf   = (ushort*)(ws + 2 * SZ);           // [b][h][q][32] head-major
  float*  samp   = (float*)(ws + 3 * SZ);            // [b][h][q][p]{x,y,w} 18.4 MB
  ushort* WvT    = (ushort*)(ws + 4 * SZ);
  ushort* WoffT  = (ushort*)(ws + 4 * SZ + 131072);
  ushort* WattnT = (ushort*)(ws + 4 * SZ + 131072 + 32768);
  ushort* WoutT  = (ushort*)(ws + 4 * SZ + 131072 + 32768 + 16384);
  ushort* aggb   = warped;  // warped is dead after gemmv; reuse for agg

  k_prep<<<3632, 256, 0, stream>>>(img, feat, Wv, Woff, Wattn, Wout,
                                   WvT, WoffT, WattnT, WoutT);
  k_warp_offattn<<<6756, 256, 25856, stream>>>(feat, grid, warped, WoffT, WattnT,
                                               boff, battn, refp, samp);
  k_gemmv<<<756, 256, 40960, stream>>>(warped, WvT, bv, vbuf);
  k_sample<<<6048, 256, 0, stream>>>(vbuf, samp, aggb);
  k_gemmout<<<756, 256, 40960, stream>>>(aggb, WoutT, bout, out, feat);
}